// Round 4
// baseline (10645.872 us; speedup 1.0000x reference)
//
#include <hip/hip_runtime.h>
#include <math.h>

// GRU scan: B=64, L=2048, H=512, IN=1.
// R4 structure: 8 groups x 64 blocks (grid 512, 2 blocks/CU).
// Group g owns batches [8g,8g+8); block j in group owns h-slice [8j,8j+8)
// (24 rows of W_hh = 3 gates x 8 h, 48KB) stationary in LDS.
// Residual exchanged through d_ws (double buffer) with per-block flag slots.
//
// Why 2 blocks/CU: R3 showed step = ~4.1K cyc VALU + ~2K LDS + ~5-6K cyc of
// exposed MALL rendezvous latency with the CU idle (Occupancy 24.5%, VALUBusy
// 34%). Two co-resident blocks from DIFFERENT groups interleave: one group's
// compute fills the other's barrier stall.
// LDS/block ~70.7KB -> exactly 2/CU; __launch_bounds__(512,4) caps VGPR at 128
// (measured 88) so occupancy is LDS-bound at 2, as intended.
//
// Bank-conflict fixes vs R3 (conflicts went 5e7->3.5e8 with f32x2+pad516):
// residual fragments read as ds_read_b128 with row pitch 516 dwords -> the 4
// lane-groups (rows 2q+bl, bases 4*(2q+bl) banks) hit disjoint bank quads.
// x_s padded to 132 so the 4-lane broadcast of x lands on distinct banks.

#define BB_ 64
#define LL_ 2048
#define HH_ 512
#define NGROUP 8
#define GBLK 64     // blocks per group
#define BGRP 8      // batches per group
#define HBLK 8      // h per block
#define NT 512      // threads per block
#define RROW 516    // res_s row pitch (floats): rows offset 4 banks
#define XROW 132    // x_s row pitch

#define FLAG_STRIDE 4               // dwords (16 B) per flag slot
#define FLAG_BYTES (NGROUP * GBLK * FLAG_STRIDE * 4)   // 8 KiB

typedef float f32x2 __attribute__((ext_vector_type(2)));
typedef float f32x4 __attribute__((ext_vector_type(4)));

template<int CTRL>
__device__ __forceinline__ float dpp_add(float x) {
    int s = __builtin_amdgcn_update_dpp(0, __float_as_int(x), CTRL, 0xF, 0xF, true);
    return x + __int_as_float(s);
}

__device__ __forceinline__ f32x4 load_f4_coherent(const float* p) {
    f32x4 r;
    asm volatile("global_load_dwordx4 %0, %1, off sc0 sc1" : "=v"(r) : "v"(p) : "memory");
    return r;
}
__device__ __forceinline__ void store_f4_coherent(float* p, f32x4 v) {
    asm volatile("global_store_dwordx4 %0, %1, off sc0 sc1" : : "v"(p), "v"(v) : "memory");
}
__device__ __forceinline__ void store_dw_coherent(unsigned* p, unsigned v) {
    asm volatile("global_store_dword %0, %1, off sc0 sc1" : : "v"(p), "v"(v) : "memory");
}
__device__ __forceinline__ void vm0() {
    asm volatile("s_waitcnt vmcnt(0)" ::: "memory");
    __builtin_amdgcn_sched_barrier(0);
}
__device__ __forceinline__ void pkfma(f32x2& acc, f32x2 a, f32x2 b) {
    asm("v_pk_fma_f32 %0, %1, %2, %0" : "+v"(acc) : "v"(a), "v"(b));
}

__global__ __launch_bounds__(NT, 4)
void gru_scan_kernel(const float* __restrict__ x,
                     const float* __restrict__ state,
                     const float* __restrict__ W_ih,
                     const float* __restrict__ W_hh,
                     const float* __restrict__ b_ih,
                     const float* __restrict__ b_hh,
                     const float* __restrict__ A,
                     float* __restrict__ out,
                     char* __restrict__ ws) {
    __shared__ float W_s[24][HH_];                    // 49152 B, stationary
    __shared__ __align__(16) float res_s[BGRP][RROW]; // 16512 B, per step
    __shared__ float x_s[BGRP][XROW];                 // 4224 B, per 128 steps
    __shared__ float wih_s[24], bih_s[24], bhh_s[24];
    __shared__ __align__(16) float res_out_s[BGRP][HBLK];  // 256 B
    __shared__ __align__(16) float out_s[BGRP][HBLK];      // 256 B

    const int tid = threadIdx.x;
    const int bid = blockIdx.x;
    const int g   = bid >> 6;       // group
    const int j   = bid & 63;       // h-slice within group
    const int b0  = g * BGRP;
    const int h0  = j * HBLK;

    const int w    = tid >> 6;      // wave 0..7 -> local h = w
    const int lane = tid & 63;
    const int bg   = lane >> 4;     // batch-pair 0..3 -> b in {2bg, 2bg+1}
    const int ksub = lane & 15;     // k split 16-way

    unsigned* flags = (unsigned*)ws;               // [NGROUP*GBLK][FLAG_STRIDE]
    unsigned* grp_flags = flags + (size_t)g * GBLK * FLAG_STRIDE;
    float* resA = (float*)(ws + FLAG_BYTES);       // [B][H]
    float* resB = resA + BB_ * HH_;                // [B][H]

    // ---- stage stationary data ----
    for (int i = tid; i < 24 * HH_; i += NT) {
        int row = i >> 9, k = i & 511;
        int gate = row >> 3, hl = row & 7;
        W_s[row][k] = W_hh[(size_t)(gate * HH_ + h0 + hl) * HH_ + k];
    }
    if (tid < 24) {
        int gate = tid >> 3, hl = tid & 7;
        int row = gate * HH_ + h0 + hl;
        wih_s[tid] = W_ih[row];   // IN == 1
        bih_s[tid] = b_ih[row];
        bhh_s[tid] = b_hh[row];
    }
    const float Aval = A[0];

    // st accumulator lives on ksub==15 lanes: [bl] for (b0+2bg+bl, h0+w)
    float st[2];
    #pragma unroll
    for (int bl = 0; bl < 2; ++bl)
        st[bl] = state[(size_t)(b0 + 2 * bg + bl) * HH_ + h0 + w];

    const f32x4* W4 = (const f32x4*)&W_s[0][0];
    const f32x4* R4 = (const f32x4*)&res_s[0][0];

    for (int t = 0; t < LL_; ++t) {
        // ---- stage x tile every 128 steps ----
        if ((t & 127) == 0) {
            for (int i = tid; i < BGRP * 128; i += NT) {
                int bb = i >> 7, kk = i & 127;
                x_s[bb][kk] = x[(size_t)(b0 + bb) * LL_ + t + kk];
            }
        }
        // ---- stage residual: 16 KB as 1024 float4, 2 per thread ----
        {
            const int c0 = tid, c1 = tid + NT;
            const int b_0 = c0 >> 7, q0 = c0 & 127;
            const int b_1 = c1 >> 7, q1 = c1 & 127;
            f32x4 v0, v1;
            if (t == 0) {
                v0 = *(const f32x4*)&state[(size_t)(b0 + b_0) * HH_ + q0 * 4];
                v1 = *(const f32x4*)&state[(size_t)(b0 + b_1) * HH_ + q1 * 4];
            } else {
                const float* rbuf = (t & 1) ? resB : resA;
                v0 = load_f4_coherent(&rbuf[(size_t)(b0 + b_0) * HH_ + q0 * 4]);
                v1 = load_f4_coherent(&rbuf[(size_t)(b0 + b_1) * HH_ + q1 * 4]);
                vm0();
            }
            *(f32x4*)&res_s[b_0][q0 * 4] = v0;
            *(f32x4*)&res_s[b_1][q1 * 4] = v1;
        }
        __syncthreads();   // (A)

        // ---- residual fragments: [bl][8] float4 (rows at 4-bank offsets) ----
        f32x4 rv4[2][8];
        #pragma unroll
        for (int bl = 0; bl < 2; ++bl) {
            const int rowb = (2 * bg + bl) * (RROW / 4);
            #pragma unroll
            for (int m = 0; m < 8; ++m)
                rv4[bl][m] = R4[rowb + m * 16 + ksub];
        }

        // ---- GEMM slice: 3 gates x 1 h x 2 b, v_pk_fma_f32 ----
        f32x2 acc2[3][2];
        #pragma unroll
        for (int gate = 0; gate < 3; ++gate) {
            acc2[gate][0] = (f32x2){0.f, 0.f};
            acc2[gate][1] = (f32x2){0.f, 0.f};
        }
        #pragma unroll
        for (int gate = 0; gate < 3; ++gate) {
            const int lr = gate * 8 + w;
            #pragma unroll
            for (int m = 0; m < 8; ++m) {
                f32x4 wv = W4[lr * 128 + m * 16 + ksub];
                f32x2 wlo = __builtin_shufflevector(wv, wv, 0, 1);
                f32x2 whi = __builtin_shufflevector(wv, wv, 2, 3);
                #pragma unroll
                for (int bl = 0; bl < 2; ++bl) {
                    f32x4 rv = rv4[bl][m];
                    f32x2 rlo = __builtin_shufflevector(rv, rv, 0, 1);
                    f32x2 rhi = __builtin_shufflevector(rv, rv, 2, 3);
                    pkfma(acc2[gate][bl], wlo, rlo);
                    pkfma(acc2[gate][bl], whi, rhi);
                }
            }
        }

        // ---- reduce over ksub via DPP row_shr; sum lands on ksub==15 ----
        float acc[3][2];
        #pragma unroll
        for (int gate = 0; gate < 3; ++gate)
            #pragma unroll
            for (int bl = 0; bl < 2; ++bl) {
                float v = acc2[gate][bl].x + acc2[gate][bl].y;
                v = dpp_add<0x111>(v);  // row_shr:1
                v = dpp_add<0x112>(v);  // row_shr:2
                v = dpp_add<0x114>(v);  // row_shr:4
                v = dpp_add<0x118>(v);  // row_shr:8
                acc[gate][bl] = v;
            }

        // ---- gates on ksub==15 lanes (8 outputs per wave) ----
        if (ksub == 15) {
            #pragma unroll
            for (int bl = 0; bl < 2; ++bl) {
                const int b = 2 * bg + bl;
                const float xv = x_s[b][t & 127];
                float hr = acc[0][bl] + bhh_s[w];
                float hz = acc[1][bl] + bhh_s[8 + w];
                float hn = acc[2][bl] + bhh_s[16 + w];
                float ir = xv * wih_s[w]      + bih_s[w];
                float iz = xv * wih_s[8 + w]  + bih_s[8 + w];
                float in_ = xv * wih_s[16 + w] + bih_s[16 + w];
                float r = 1.f / (1.f + __expf(-(ir + hr)));
                float z = 1.f / (1.f + __expf(-(iz + hz)));
                float n = tanhf(in_ + r * hn);
                float oldr = res_s[b][h0 + w];
                float nr = (1.f - z) * n + z * oldr;
                st[bl] += Aval * nr;
                res_out_s[b][w] = nr;
                out_s[b][w] = st[bl];
            }
        }
        __syncthreads();   // (B) staging visible to wave 0

        if (w == 0) {
            float* wbuf = (t & 1) ? resA : resB;
            const unsigned target = (unsigned)(t + 1);
            // coherent residual store: 16 x 16B (8 b x 32 B slice)
            if (lane < 16) {
                const int b = lane >> 1, p = lane & 1;
                store_f4_coherent(&wbuf[(size_t)(b0 + b) * HH_ + h0 + p * 4],
                                  *(f32x4*)&res_out_s[b][p * 4]);
            }
            vm0();                       // drain residual stores (wave 0 only)
            if (lane == 0)
                store_dw_coherent(&grp_flags[j * FLAG_STRIDE], target);
            // out stores: plain cached, issued after flag -> overlap poll
            if (lane < 16) {
                const int b = lane >> 1, p = lane & 1;
                *(f32x4*)&out[((size_t)(b0 + b) * LL_ + t) * HH_ + h0 + p * 4] =
                    *(f32x4*)&out_s[b][p * 4];
            }
            // poll all 64 flags of the group (one lane per flag)
            unsigned v;
            do {
                __builtin_amdgcn_s_sleep(1);
                v = __hip_atomic_load(&grp_flags[lane * FLAG_STRIDE],
                                      __ATOMIC_RELAXED, __HIP_MEMORY_SCOPE_AGENT);
            } while (!__all((int)(v >= target)));
        }
        __syncthreads();   // (C)
    }

    // ---- final state ----
    if (ksub == 15) {
        #pragma unroll
        for (int bl = 0; bl < 2; ++bl) {
            const int bglob = b0 + 2 * bg + bl;
            out[(size_t)BB_ * LL_ * HH_ + (size_t)bglob * HH_ + h0 + w] = st[bl];
        }
    }
}

extern "C" void kernel_launch(void* const* d_in, const int* in_sizes, int n_in,
                              void* d_out, int out_size, void* d_ws, size_t ws_size,
                              hipStream_t stream) {
    (void)in_sizes; (void)n_in; (void)out_size; (void)ws_size;
    const float* x     = (const float*)d_in[0];
    const float* state = (const float*)d_in[1];
    const float* W_ih  = (const float*)d_in[2];
    const float* W_hh  = (const float*)d_in[3];
    const float* b_ih  = (const float*)d_in[4];
    const float* b_hh  = (const float*)d_in[5];
    const float* A     = (const float*)d_in[6];

    // zero the flag array (d_ws is re-poisoned to 0xAA before every launch)
    hipMemsetAsync(d_ws, 0, FLAG_BYTES, stream);
    hipLaunchKernelGGL(gru_scan_kernel, dim3(NGROUP * GBLK), dim3(NT), 0, stream,
                       x, state, W_ih, W_hh, b_ih, b_hh, A,
                       (float*)d_out, (char*)d_ws);
}